// Round 14
// baseline (1203.365 us; speedup 1.0000x reference)
//
#include <hip/hip_runtime.h>
#include <math.h>

#define N_V 5000
#define N_F 10000
#define NNZ 480000
#define LAYERS 30
#define STC 4096   // stat slot stride: 8 per-XCD copies x 512 floats
#define SCAP 1200  // staging capacity per (XCD copy, bucket); 64 buckets/op

typedef short short8 __attribute__((ext_vector_type(8)));
typedef float f32x4 __attribute__((ext_vector_type(4)));
union BFu { uint4 u; short8 s8; short s[8]; unsigned short us[8]; };

__device__ __forceinline__ float eluf(float x){ return x>0.f ? x : expm1f(x); }
__device__ __forceinline__ unsigned short f2bf(float f){
  unsigned u = __float_as_uint(f);
  unsigned r = (u + 0x7fffu + ((u>>16)&1u)) >> 16;
  return (unsigned short)r;
}
__device__ __forceinline__ float bf2f(unsigned short u){
  return __uint_as_float((unsigned)u << 16);
}

// ---------------- CSR build ----------------
// Per-XCD histogram copies: copy = blockIdx&7 -> atomic lines stay in one L2.
__global__ void hist_both(const int* __restrict__ Di_rows, const int* __restrict__ DiA_rows,
                          int* __restrict__ Di_hist, int* __restrict__ DA_hist){
  int e = blockIdx.x*256 + threadIdx.x;
  int c = blockIdx.x & 7;
  if(e < NNZ){
    atomicAdd(&Di_hist[c*40000 + Di_rows[e]], 1);
    atomicAdd(&DA_hist[c*20000 + DiA_rows[e]], 1);
  }
}

__global__ void chunkscan(const int* __restrict__ Di_hist, int* __restrict__ Di_ptr,
                          const int* __restrict__ DA_hist, int* __restrict__ DA_ptr,
                          int* __restrict__ bsumDi, int* __restrict__ bsumDA){
  __shared__ int ish[256];
  int b = blockIdx.x, tid = threadIdx.x;
  const int nchDi = 157;
  const int* hist; int* optr; int n; int cb; int* bs;
  if(b < nchDi){ hist=Di_hist; optr=Di_ptr; n=40000; cb=b; bs=bsumDi; }
  else { hist=DA_hist; optr=DA_ptr; n=20000; cb=b-nchDi; bs=bsumDA; }
  int i = cb*256 + tid;
  int v = 0;
  if(i<n){
    #pragma unroll
    for(int c8=0;c8<8;++c8) v += hist[c8*n + i];
  }
  ish[tid]=v; __syncthreads();
  for(int off=1; off<256; off<<=1){
    int t = (tid>=off)? ish[tid-off] : 0;
    __syncthreads(); ish[tid]+=t; __syncthreads();
  }
  if(i<n) optr[i] = ish[tid]-v;
  if(tid==255) bs[cb]=ish[255];
}

__global__ void topscan(int* __restrict__ bsumDi, int* __restrict__ bsumDA){
  __shared__ int ish[256];
  int tid=threadIdx.x;
  int* bs = (blockIdx.x==0) ? bsumDi : bsumDA;
  int n  = (blockIdx.x==0) ? 157 : 79;
  int v = (tid<n)? bs[tid] : 0;
  ish[tid]=v; __syncthreads();
  for(int off=1; off<256; off<<=1){
    int t=(tid>=off)? ish[tid-off]:0;
    __syncthreads(); ish[tid]+=t; __syncthreads();
  }
  if(tid<n) bs[tid]=ish[tid]-v;
}

__global__ void addback(int* __restrict__ Di_ptr, int* __restrict__ Di_cur,
                        const int* __restrict__ bsumDi,
                        int* __restrict__ DA_ptr, int* __restrict__ DA_cur,
                        const int* __restrict__ bsumDA){
  int stride = gridDim.x*256;
  int base = blockIdx.x*256 + threadIdx.x;
  for(int i=base;i<40000;i+=stride){ int v=Di_ptr[i]+bsumDi[i>>8]; Di_ptr[i]=v; Di_cur[i]=v; }
  for(int i=base;i<20000;i+=stride){ int v=DA_ptr[i]+bsumDA[i>>8]; DA_ptr[i]=v; DA_cur[i]=v; }
  if(base==0){ Di_ptr[40000]=NNZ; DA_ptr[20000]=NNZ; }
}

// ---- scatter phase A: append edges to per-(XCD,64-bucket) staging bins ------
__global__ void stage_pairs(const int* __restrict__ Di_rows, const int* __restrict__ Di_cols,
                            const float* __restrict__ Di_vals,
                            const int* __restrict__ DiA_rows, const int* __restrict__ DiA_cols,
                            const float* __restrict__ DiA_vals,
                            uint2* __restrict__ stDi, uint2* __restrict__ stDA,
                            int* __restrict__ bcnt,
                            int* __restrict__ Di_cur, float2* __restrict__ Di_pairs,
                            int* __restrict__ DA_cur, float2* __restrict__ DA_pairs){
  __shared__ int lh[128], lb[128];
  int tid = threadIdx.x;
  if(tid < 128) lh[tid] = 0;
  __syncthreads();
  int e = blockIdx.x*256 + tid;
  int c = blockIdx.x & 7;
  bool ok = e < NNZ;
  int rDi=0,cDi=0,bDi=0,rkDi=0,rDA=0,cDA=0,bDA=0,rkDA=0;
  float vDi=0.f,vDA=0.f;
  if(ok){
    rDi = Di_rows[e]; cDi = Di_cols[e]; vDi = Di_vals[e];
    rDA = DiA_rows[e]; cDA = DiA_cols[e]; vDA = DiA_vals[e];
    bDi = rDi/625;    // 64 buckets over [0,40000)
    bDA = rDA/313;    // 64 buckets over [0,20000)
    rkDi = atomicAdd(&lh[bDi], 1);
    rkDA = atomicAdd(&lh[64+bDA], 1);
  }
  __syncthreads();
  if(tid < 128) lb[tid] = atomicAdd(&bcnt[c*128 + tid], lh[tid]);
  __syncthreads();
  if(ok){
    int off = lb[bDi] + rkDi;
    if(off < SCAP)
      stDi[(c*64+bDi)*SCAP + off] = make_uint2((unsigned)rDi | ((unsigned)cDi<<16), __float_as_uint(vDi));
    else { int pos = atomicAdd(&Di_cur[rDi],1); Di_pairs[pos] = make_float2(__int_as_float(cDi), vDi); }
    off = lb[64+bDA] + rkDA;
    if(off < SCAP)
      stDA[(c*64+bDA)*SCAP + off] = make_uint2((unsigned)rDA | ((unsigned)cDA<<16), __float_as_uint(vDA));
    else { int pos = atomicAdd(&DA_cur[rDA],1); DA_pairs[pos] = make_float2(__int_as_float(cDA), vDA); }
  }
}

// ---- scatter phase B: place staged edges into CSR positions ----------------
__global__ void place_pairs(const uint2* __restrict__ stDi, const uint2* __restrict__ stDA,
                            const int* __restrict__ bcnt,
                            int* __restrict__ Di_cur, float2* __restrict__ Di_pairs,
                            int* __restrict__ DA_cur, float2* __restrict__ DA_pairs){
  int bg  = blockIdx.x & 127;
  int sub = blockIdx.x >> 7;                   // 0..3
  bool isDA = bg >= 64;
  int b = bg & 63;
  const uint2* st = isDA ? stDA : stDi;
  int* cur = isDA ? DA_cur : Di_cur;
  float2* pairs = isDA ? DA_pairs : Di_pairs;
  for(int c=0;c<8;++c){
    int n = min(bcnt[c*128 + bg], SCAP);
    const uint2* base = st + (size_t)(c*64+b)*SCAP;
    for(int j = sub*256 + threadIdx.x; j < n; j += 4*256){
      uint2 p = base[j];
      int row = p.x & 0xFFFF;
      int col = p.x >> 16;
      int pos = atomicAdd(&cur[row], 1);
      pairs[pos] = make_float2(__int_as_float(col), __uint_as_float(p.y));
    }
  }
}

// ---------------- weight convert: Wt[(2i+m)*128 + n][k] = bf16(W_m[i][k][n]) ----
__global__ void wconv(const float* __restrict__ W0, const float* __restrict__ Wl1,
                      unsigned short* __restrict__ Wt){
  __shared__ float tile[32][129];
  int b  = blockIdx.x >> 3;       // 60 = i*2+m
  int kt = blockIdx.x & 7;        // 8 k-tiles of 32
  int i = b>>1, m = b&1;
  const float* W = (m ? Wl1 : W0) + (size_t)i*32768;
  unsigned short* out = Wt + (size_t)b*32768;
  int tid = threadIdx.x;
  int n = tid & 127, kr = tid >> 7;            // 2 k-rows x 128 n per iter
  for(int kk = kr; kk < 32; kk += 2)
    tile[kk][n] = W[(kt*32 + kk)*128 + n];
  __syncthreads();
  int kp = tid & 31, n8 = tid >> 5;            // 8 n x 32 k' per iter
  for(int nn = n8; nn < 128; nn += 8)
    out[nn*256 + kt*32 + kp] = f2bf(tile[kp][nn]);
}

// ---------------- conv1 (+ elu stats) + odd-bias precompute ----
__global__ void conv1_kernel(const float* __restrict__ in, const float* __restrict__ W_in,
                             const float* __restrict__ b_in,
                             const float* __restrict__ be0, const float* __restrict__ be1,
                             const unsigned short* __restrict__ Wt,
                             float* __restrict__ v_raw, unsigned short* __restrict__ elu_v,
                             float* __restrict__ st1, float* __restrict__ oddb){
  __shared__ float pool[256];
  int tid = threadIdx.x;
  int stride = gridDim.x*256;
  int cpy = (blockIdx.x&7)*512;
  float ls=0.f, ls2=0.f;
  for(int idx = blockIdx.x*256+tid; idx < N_V*128; idx += stride){
    int n = idx>>7, c = idx&127;
    float v = b_in[c] + in[n*3]*W_in[c] + in[n*3+1]*W_in[128+c] + in[n*3+2]*W_in[256+c];
    v_raw[idx] = v;
    float ev = eluf(v);
    elu_v[idx] = f2bf(ev);
    ls += ev; ls2 += ev*ev;
  }
  int ch = tid & 127;
  pool[tid]=ls; __syncthreads();
  if(tid<128) atomicAdd(&st1[cpy+ch], pool[tid]+pool[tid+128]);
  __syncthreads();
  pool[tid]=ls2; __syncthreads();
  if(tid<128) atomicAdd(&st1[cpy+256+ch], pool[tid]+pool[tid+128]);
  for(int item = blockIdx.x*256+tid; item < LAYERS*2*128; item += stride){
    int b = item >> 7;          // i*2+m
    int i = b >> 1, m = b & 1;
    int j = item & 127;
    const float* bp = (m ? be1 : be0) + i*256 + 128;
    const unsigned short* wp = Wt + (size_t)b*32768 + j*256 + 128;
    float s = 0.f;
    #pragma unroll 8
    for(int k=0;k<128;++k) s += bp[k]*bf2f(wp[k]);
    oddb[item] = s;
  }
}

// ---------------- SpMM: 8 rows per wave, 8 lanes per row (4 ch each) ----------
// Cooperative pairs load + shfl distribute; bf16 output; per-XCD fp32 stats.
__global__ __launch_bounds__(256) void spmm_bn(
    const int* __restrict__ ptr, const float2* __restrict__ pairs,
    const unsigned short* __restrict__ x, unsigned short* __restrict__ y, int nrows,
    float* __restrict__ stslot){
  __shared__ float pool[512];
  int tid = threadIdx.x;
  int w = tid>>6, lane = tid&63;
  int slot = lane>>3, jg = lane&7;
  int gbase = slot*8;                 // first lane of this row-group
  int row = blockIdx.x*32 + w*8 + slot;
  float4 acc = make_float4(0,0,0,0);
  if(row < nrows){
    int s0 = ptr[row], e0 = ptr[row+1];
    int last = e0 - 1;
    for(int base = s0; base < e0; base += 16){
      float2 pa = pairs[min(base + jg, last)];
      ushort4 xv[16]; float wgt[16];
      #pragma unroll
      for(int u=0;u<8;++u){
        float px = __shfl(pa.x, gbase + u);
        wgt[u] = (base + u <= last) ? __shfl(pa.y, gbase + u) : 0.f;
        xv[u] = *(const ushort4*)&x[(__float_as_int(px)<<5) + jg*4];
      }
      bool half2 = (base + 8 <= last);          // uniform within the group
      if(half2){
        float2 pb = pairs[min(base + 8 + jg, last)];
        #pragma unroll
        for(int u=0;u<8;++u){
          float px = __shfl(pb.x, gbase + u);
          wgt[8+u] = (base + 8 + u <= last) ? __shfl(pb.y, gbase + u) : 0.f;
          xv[8+u] = *(const ushort4*)&x[(__float_as_int(px)<<5) + jg*4];
        }
      }
      #pragma unroll
      for(int u=0;u<8;++u){
        acc.x += wgt[u]*bf2f(xv[u].x);
        acc.y += wgt[u]*bf2f(xv[u].y);
        acc.z += wgt[u]*bf2f(xv[u].z);
        acc.w += wgt[u]*bf2f(xv[u].w);
      }
      if(half2){
        #pragma unroll
        for(int u=8;u<16;++u){
          acc.x += wgt[u]*bf2f(xv[u].x);
          acc.y += wgt[u]*bf2f(xv[u].y);
          acc.z += wgt[u]*bf2f(xv[u].z);
          acc.w += wgt[u]*bf2f(xv[u].w);
        }
      }
    }
    ushort4 yo;
    yo.x = f2bf(acc.x); yo.y = f2bf(acc.y); yo.z = f2bf(acc.z); yo.w = f2bf(acc.w);
    *(ushort4*)&y[(row<<5) + jg*4] = yo;
  }
  float4 ls2 = make_float4(acc.x*acc.x, acc.y*acc.y, acc.z*acc.z, acc.w*acc.w);
  acc.x += __shfl_xor(acc.x, 32); acc.y += __shfl_xor(acc.y, 32);
  acc.z += __shfl_xor(acc.z, 32); acc.w += __shfl_xor(acc.w, 32);
  ls2.x += __shfl_xor(ls2.x, 32); ls2.y += __shfl_xor(ls2.y, 32);
  ls2.z += __shfl_xor(ls2.z, 32); ls2.w += __shfl_xor(ls2.w, 32);
  if(slot < 4) *(float4*)&pool[w*128 + slot*32 + jg*4] = acc;
  __syncthreads();
  int cpy = (blockIdx.x&7)*512;
  if(tid < 128){
    int c = (tid + (blockIdx.x<<3)) & 127;
    atomicAdd(&stslot[cpy+128+c], pool[c]+pool[128+c]+pool[256+c]+pool[384+c]);
  }
  __syncthreads();
  if(slot < 4) *(float4*)&pool[w*128 + slot*32 + jg*4] = ls2;
  __syncthreads();
  if(tid < 128){
    int c = (tid + (blockIdx.x<<3)) & 127;
    atomicAdd(&stslot[cpy+384+c], pool[c]+pool[128+c]+pool[256+c]+pool[384+c]);
  }
}

// ---------------- MFMA GEMM: A0 bf16 (k<128), A1 bf16 (k>=128, spmm out). ----
// A/B fragments are PREFETCHED into registers BEFORE the stat prologue, so
// the global-load latency overlaps the stat-load + __syncthreads chain
// (the barrier otherwise fences the loads below it). K fully unrolled.
// Stats in: sum of 8 per-XCD copies. Stats out: per-XCD copy (blockIdx&7).
template<int KT>
__global__ __launch_bounds__(256) void gemm_mfma(
    const unsigned short* __restrict__ A0, const unsigned short* __restrict__ A1,
    const float* __restrict__ st, float invM,
    const float* __restrict__ g, const float* __restrict__ be,
    const unsigned short* __restrict__ Wt, const float* __restrict__ bias,
    const float* __restrict__ bias2, const float* __restrict__ resid,
    float* __restrict__ out_raw, unsigned short* __restrict__ out_elu,
    float* __restrict__ stE, float* __restrict__ stR, int M)
{
  __shared__ float ab[256], bb[256];
  int tid = threadIdx.x;
  int wave = tid>>6, lane = tid&63;
  int ln = lane&15, q = lane>>4;
  int r0 = blockIdx.x*16;
  int c0 = wave*32;
  int kq = q*8;
  int arow = r0 + ln;
  bool aok = arow < M;

  // ---- prefetch A (all K) and B (all K) into registers ----
  uint4 araw[KT/32];
  #pragma unroll
  for(int kb=0; kb<KT; kb+=32){
    int kg = kb + kq;
    if(aok){
      const unsigned short* Ap = (A1 && kb >= 128) ? &A1[arow*128 + kg - 128]
                                                   : &A0[arow*128 + kg];
      araw[kb/32] = *(const uint4*)Ap;
    } else {
      araw[kb/32] = make_uint4(0,0,0,0);
    }
  }
  uint4 braw[KT/16];
  #pragma unroll
  for(int kb=0; kb<KT; kb+=32){
    #pragma unroll
    for(int nb=0;nb<2;++nb){
      int n = c0 + nb*16 + ln;
      braw[(kb/32)*2+nb] = *(const uint4*)&Wt[n*256 + kb + kq];
    }
  }

  // ---- stat prologue (overlapped with the prefetch latency above) ----
  if(tid < KT){
    float s1 = 0.f, s2v = 0.f;
    #pragma unroll
    for(int c8=0;c8<8;++c8){ s1 += st[c8*512 + tid]; s2v += st[c8*512 + 256 + tid]; }
    float mean = s1*invM;
    float var  = fmaxf(s2v*invM - mean*mean, 0.f);
    float aa   = g[tid]*rsqrtf(var + 1e-5f);
    ab[tid] = aa; bb[tid] = be[tid] - mean*aa;
  }
  __syncthreads();

  f32x4 acc[2] = {};
  #pragma unroll
  for(int kb=0; kb<KT; kb+=32){
    int kg = kb + kq;
    BFu af;
    if(!aok){
      #pragma unroll
      for(int j2=0;j2<8;++j2) af.us[j2] = 0;
    } else {
      BFu raw; raw.u = araw[kb/32];
      #pragma unroll
      for(int j2=0;j2<8;++j2) af.us[j2] = f2bf(fmaf(bf2f(raw.us[j2]), ab[kg+j2], bb[kg+j2]));
    }
    #pragma unroll
    for(int nb=0;nb<2;++nb){
      BFu bfv; bfv.u = braw[(kb/32)*2+nb];
      acc[nb] = __builtin_amdgcn_mfma_f32_16x16x32_bf16(af.s8, bfv.s8, acc[nb], 0, 0, 0);
    }
  }

  int rbase = r0 + q*4;
  bool wantR = (stR != nullptr);
  int cpy = (blockIdx.x&7)*512;
  #pragma unroll
  for(int nb=0;nb<2;++nb){
    int col = c0 + nb*16 + ln;
    float bsum = bias[col] + (bias2 ? bias2[col] : 0.f);
    float s=0.f, s2=0.f, rs=0.f, rs2=0.f;
    #pragma unroll
    for(int reg=0;reg<4;++reg){
      int row = rbase + reg;
      bool ok = row < M;
      float v = acc[nb][reg] + bsum;
      if(resid && ok) v += resid[row*128 + col];
      float ve = eluf(v);
      if(ok){
        if(out_raw) out_raw[row*128 + col] = v;
        if(out_elu) out_elu[row*128 + col] = f2bf(ve);
        s += ve; s2 += ve*ve;
        if(wantR){ rs += v; rs2 += v*v; }
      }
    }
    s  += __shfl_xor(s, 16);  s  += __shfl_xor(s, 32);
    s2 += __shfl_xor(s2, 16); s2 += __shfl_xor(s2, 32);
    if(wantR){
      rs  += __shfl_xor(rs, 16);  rs  += __shfl_xor(rs, 32);
      rs2 += __shfl_xor(rs2, 16); rs2 += __shfl_xor(rs2, 32);
    }
    if(q==0){
      if(stE){ atomicAdd(&stE[cpy+col], s); atomicAdd(&stE[cpy+256+col], s2); }
      if(wantR){ atomicAdd(&stR[cpy+col], rs); atomicAdd(&stR[cpy+256+col], rs2); }
    }
  }
}

// ---------------- final: BN(v) @ W_out + b_out, elu ------------------
__global__ void final_kernel(const float* __restrict__ v_raw, const float* __restrict__ st,
                             const float* __restrict__ g2, const float* __restrict__ be2,
                             const float* __restrict__ W_out, const float* __restrict__ b_out,
                             float* __restrict__ out){
  __shared__ float pool[256];
  int tid = threadIdx.x; int half = tid>>7, k = tid&127;
  float s1 = 0.f, s2v = 0.f;
  #pragma unroll
  for(int c8=0;c8<8;++c8){ s1 += st[c8*512 + k]; s2v += st[c8*512 + 256 + k]; }
  float mean = s1*(1.f/N_V);
  float var = fmaxf(s2v*(1.f/N_V) - mean*mean, 0.f);
  float aa = g2[k]*rsqrtf(var+1e-5f);
  float scale = aa*W_out[k];
  float cons = (be2[k]-mean*aa)*W_out[k];
  int r = blockIdx.x*2 + half;
  float val = v_raw[r*128+k]*scale + cons;
  pool[tid]=val; __syncthreads();
  for(int s=64;s>=1;s>>=1){ if(k<s) pool[tid]+=pool[tid+s]; __syncthreads(); }
  if(k==0) out[r] = eluf(pool[tid] + b_out[0]);
}

extern "C" void kernel_launch(void* const* d_in, const int* in_sizes, int n_in,
                              void* d_out, int out_size, void* d_ws, size_t ws_size,
                              hipStream_t stream){
  const float* inputs  = (const float*)d_in[0];
  const int*   Di_rows = (const int*)d_in[2];
  const int*   Di_cols = (const int*)d_in[3];
  const float* Di_vals = (const float*)d_in[4];
  const int*   DiA_rows= (const int*)d_in[5];
  const int*   DiA_cols= (const int*)d_in[6];
  const float* DiA_vals= (const float*)d_in[7];
  const float* W_in = (const float*)d_in[8];  const float* b_in = (const float*)d_in[9];
  const float* g0  = (const float*)d_in[10];  const float* be0 = (const float*)d_in[11];
  const float* W0  = (const float*)d_in[12];  const float* b0  = (const float*)d_in[13];
  const float* g1  = (const float*)d_in[14];  const float* be1 = (const float*)d_in[15];
  const float* Wl1 = (const float*)d_in[16];  const float* bl1 = (const float*)d_in[17];
  const float* g2  = (const float*)d_in[18];  const float* be2 = (const float*)d_in[19];
  const float* W_out = (const float*)d_in[20]; const float* b_out = (const float*)d_in[21];

  float* ws = (float*)d_ws;
  float* v_raw = ws;                                        // 640000 f
  unsigned short* elu_v0 = (unsigned short*)(ws + 640000);  // 640000 us
  unsigned short* elu_v1 = (unsigned short*)(ws + 960000);  // 640000 us
  unsigned short* elu_f0 = (unsigned short*)(ws + 1280000); // 1280000 us -> f 1280000..1920000
  unsigned short* Dv16  = (unsigned short*)(ws + 2560000);  // 1280000 us (bf16)
  unsigned short* DAf16 = (unsigned short*)(ws + 3840000);  // 640000 us (bf16)
  float* st    = ws + 4480000;             // 64 slots x 4096 = 262144 f (slot 63 = bcnt)
  float* oddb  = ws + 4742144;             // 7680
  int* Di_ptr  = (int*)(ws + 4749824);     // 40001
  int* DA_ptr  = (int*)(ws + 4789825);     // 20001
  int* Di_cur  = (int*)(ws + 4809826);     // 40000 (init by addback)
  int* DA_cur  = (int*)(ws + 4849826);     // 20000 (init by addback)
  float2* Di_pairs = (float2*)(ws + 4869826);  // 960000 floats (even -> 8B aligned)
  float2* DA_pairs = (float2*)(ws + 5829826);  // 960000 floats
  int* bsumDi  = (int*)(ws + 6789826);     // 256
  int* bsumDA  = (int*)(ws + 6790082);     // 128
  unsigned short* Wt = (unsigned short*)(ws + 6790212);     // 60*32768 us
  unsigned short* elu_f1 = (unsigned short*)(ws + 7773252); // 1280000 us
  unsigned short* elu_x1 = Dv16;                            // odd layers only
  // staging (setup-only) spans the dead region f 1280000..3737600.
  uint2* stDi = (uint2*)(ws + 1280000);    // 8*64*1200 uint2 -> ends 2508800
  uint2* stDA = (uint2*)(ws + 2508800);    // -> ends 3737600
  // hist copies alias the (not-yet-written) Di_pairs region
  int* Di_hist = (int*)Di_pairs;           // 320000 ints
  int* DA_hist = Di_hist + 320000;         // 160000 ints (contiguous -> one memset)
  int* bcnt    = (int*)(st + (size_t)63*STC);  // 8*128=1024 ints, zeroed by st memset

  unsigned short* Vb[2] = {elu_v0, elu_v1};
  unsigned short* Fb[2] = {elu_f0, elu_f1};

  hipMemsetAsync(st, 0, (size_t)64*STC*sizeof(float), stream);
  hipMemsetAsync(Di_hist, 0, (size_t)480000*sizeof(int), stream);

  hist_both<<<1875, 256, 0, stream>>>(Di_rows, DiA_rows, Di_hist, DA_hist);
  chunkscan<<<236, 256, 0, stream>>>(Di_hist, Di_ptr, DA_hist, DA_ptr, bsumDi, bsumDA);
  topscan<<<2, 256, 0, stream>>>(bsumDi, bsumDA);
  addback<<<236, 256, 0, stream>>>(Di_ptr, Di_cur, bsumDi, DA_ptr, DA_cur, bsumDA);
  stage_pairs<<<1875, 256, 0, stream>>>(Di_rows, Di_cols, Di_vals,
                                        DiA_rows, DiA_cols, DiA_vals,
                                        stDi, stDA, bcnt,
                                        Di_cur, Di_pairs, DA_cur, DA_pairs);
  place_pairs<<<512, 256, 0, stream>>>(stDi, stDA, bcnt,
                                       Di_cur, Di_pairs, DA_cur, DA_pairs);
  // elu_f0 overlaps the staging region -> zero it only after place_pairs.
  hipMemsetAsync(elu_f0, 0, (size_t)1280000*sizeof(unsigned short), stream);
  wconv<<<480, 256, 0, stream>>>(W0, Wl1, Wt);
  conv1_kernel<<<640, 256, 0, stream>>>(inputs, W_in, b_in, be0, be1, Wt,
                                        v_raw, elu_v0, st + STC, oddb);

  int pv = 0, pf = 0;
  for(int i=0;i<LAYERS;++i){
    if((i&1)==0){
      float* S0  = st + (size_t)(2*i)*STC;
      float* S1b = st + (size_t)(2*i+1)*STC;
      spmm_bn<<<1250, 256, 0, stream>>>(Di_ptr, Di_pairs, Vb[pv], Dv16, 40000, S0);
      gemm_mfma<256><<<625, 256, 0, stream>>>(Fb[pf], Dv16, S0, 1.f/N_F, g0+i*256, be0+i*256,
                                         Wt + (size_t)(2*i)*32768, b0+i*128, nullptr,
                                         nullptr, nullptr, Fb[pf^1],
                                         st+(size_t)(2*(i+2))*STC, nullptr, N_F);
      pf ^= 1;
      spmm_bn<<<625, 256, 0, stream>>>(DA_ptr, DA_pairs, Fb[pf], DAf16, 20000, S1b);
      gemm_mfma<256><<<313, 256, 0, stream>>>(Vb[pv], DAf16, S1b, 1.f/N_V, g1+i*256, be1+i*256,
                                         Wt + (size_t)(2*i+1)*32768, bl1+i*128, nullptr,
                                         v_raw, v_raw, Vb[pv^1],
                                         st+(size_t)(2*(i+1))*STC, nullptr, N_V);
      pv ^= 1;
    } else {
      float* S0  = st + (size_t)(2*i)*STC;
      float* S1b = st + (size_t)(2*i+1)*STC;
      gemm_mfma<128><<<313, 256, 0, stream>>>(Vb[pv], nullptr, S0, 1.f/N_V, g0+i*256, be0+i*256,
                                         Wt + (size_t)(2*i)*32768, b0+i*128, oddb+i*256,
                                         nullptr, nullptr, elu_x1,
                                         S1b, nullptr, N_V);
      float* stE = (i==LAYERS-1) ? nullptr : st+(size_t)(2*i+3)*STC;
      float* stR = (i==LAYERS-1) ? st+(size_t)62*STC : nullptr;
      gemm_mfma<128><<<313, 256, 0, stream>>>(elu_x1, nullptr, S1b, 1.f/N_V, g1+i*256, be1+i*256,
                                         Wt + (size_t)(2*i+1)*32768, bl1+i*128, oddb+i*256+128,
                                         v_raw, v_raw, Vb[pv],
                                         stE, stR, N_V);
    }
  }
  final_kernel<<<2500, 256, 0, stream>>>(v_raw, st+(size_t)62*STC, g2, be2, W_out, b_out,
                                         (float*)d_out);
}

// Round 15
// 1153.651 us; speedup vs baseline: 1.0431x; 1.0431x over previous
//
#include <hip/hip_runtime.h>
#include <math.h>

#define N_V 5000
#define N_F 10000
#define NNZ 480000
#define LAYERS 30
#define STC 4096   // stat slot stride: 8 per-XCD copies x 512 floats
#define SCAP 1200  // staging capacity per (XCD copy, bucket); 64 buckets/op

typedef short short8 __attribute__((ext_vector_type(8)));
typedef float f32x4 __attribute__((ext_vector_type(4)));
union BFu { uint4 u; short8 s8; short s[8]; unsigned short us[8]; };

__device__ __forceinline__ float eluf(float x){ return x>0.f ? x : expm1f(x); }
__device__ __forceinline__ unsigned short f2bf(float f){
  unsigned u = __float_as_uint(f);
  unsigned r = (u + 0x7fffu + ((u>>16)&1u)) >> 16;
  return (unsigned short)r;
}
__device__ __forceinline__ float bf2f(unsigned short u){
  return __uint_as_float((unsigned)u << 16);
}

// ---------------- CSR build ----------------
// Per-XCD histogram copies: copy = blockIdx&7 -> atomic lines stay in one L2.
__global__ void hist_both(const int* __restrict__ Di_rows, const int* __restrict__ DiA_rows,
                          int* __restrict__ Di_hist, int* __restrict__ DA_hist){
  int e = blockIdx.x*256 + threadIdx.x;
  int c = blockIdx.x & 7;
  if(e < NNZ){
    atomicAdd(&Di_hist[c*40000 + Di_rows[e]], 1);
    atomicAdd(&DA_hist[c*20000 + DiA_rows[e]], 1);
  }
}

__global__ void chunkscan(const int* __restrict__ Di_hist, int* __restrict__ Di_ptr,
                          const int* __restrict__ DA_hist, int* __restrict__ DA_ptr,
                          int* __restrict__ bsumDi, int* __restrict__ bsumDA){
  __shared__ int ish[256];
  int b = blockIdx.x, tid = threadIdx.x;
  const int nchDi = 157;
  const int* hist; int* optr; int n; int cb; int* bs;
  if(b < nchDi){ hist=Di_hist; optr=Di_ptr; n=40000; cb=b; bs=bsumDi; }
  else { hist=DA_hist; optr=DA_ptr; n=20000; cb=b-nchDi; bs=bsumDA; }
  int i = cb*256 + tid;
  int v = 0;
  if(i<n){
    #pragma unroll
    for(int c8=0;c8<8;++c8) v += hist[c8*n + i];
  }
  ish[tid]=v; __syncthreads();
  for(int off=1; off<256; off<<=1){
    int t = (tid>=off)? ish[tid-off] : 0;
    __syncthreads(); ish[tid]+=t; __syncthreads();
  }
  if(i<n) optr[i] = ish[tid]-v;
  if(tid==255) bs[cb]=ish[255];
}

__global__ void topscan(int* __restrict__ bsumDi, int* __restrict__ bsumDA){
  __shared__ int ish[256];
  int tid=threadIdx.x;
  int* bs = (blockIdx.x==0) ? bsumDi : bsumDA;
  int n  = (blockIdx.x==0) ? 157 : 79;
  int v = (tid<n)? bs[tid] : 0;
  ish[tid]=v; __syncthreads();
  for(int off=1; off<256; off<<=1){
    int t=(tid>=off)? ish[tid-off]:0;
    __syncthreads(); ish[tid]+=t; __syncthreads();
  }
  if(tid<n) bs[tid]=ish[tid]-v;
}

__global__ void addback(int* __restrict__ Di_ptr, int* __restrict__ Di_cur,
                        const int* __restrict__ bsumDi,
                        int* __restrict__ DA_ptr, int* __restrict__ DA_cur,
                        const int* __restrict__ bsumDA){
  int stride = gridDim.x*256;
  int base = blockIdx.x*256 + threadIdx.x;
  for(int i=base;i<40000;i+=stride){ int v=Di_ptr[i]+bsumDi[i>>8]; Di_ptr[i]=v; Di_cur[i]=v; }
  for(int i=base;i<20000;i+=stride){ int v=DA_ptr[i]+bsumDA[i>>8]; DA_ptr[i]=v; DA_cur[i]=v; }
  if(base==0){ Di_ptr[40000]=NNZ; DA_ptr[20000]=NNZ; }
}

// ---- scatter phase A: append edges to per-(XCD,64-bucket) staging bins ------
__global__ void stage_pairs(const int* __restrict__ Di_rows, const int* __restrict__ Di_cols,
                            const float* __restrict__ Di_vals,
                            const int* __restrict__ DiA_rows, const int* __restrict__ DiA_cols,
                            const float* __restrict__ DiA_vals,
                            uint2* __restrict__ stDi, uint2* __restrict__ stDA,
                            int* __restrict__ bcnt,
                            int* __restrict__ Di_cur, float2* __restrict__ Di_pairs,
                            int* __restrict__ DA_cur, float2* __restrict__ DA_pairs){
  __shared__ int lh[128], lb[128];
  int tid = threadIdx.x;
  if(tid < 128) lh[tid] = 0;
  __syncthreads();
  int e = blockIdx.x*256 + tid;
  int c = blockIdx.x & 7;
  bool ok = e < NNZ;
  int rDi=0,cDi=0,bDi=0,rkDi=0,rDA=0,cDA=0,bDA=0,rkDA=0;
  float vDi=0.f,vDA=0.f;
  if(ok){
    rDi = Di_rows[e]; cDi = Di_cols[e]; vDi = Di_vals[e];
    rDA = DiA_rows[e]; cDA = DiA_cols[e]; vDA = DiA_vals[e];
    bDi = rDi/625;    // 64 buckets over [0,40000)
    bDA = rDA/313;    // 64 buckets over [0,20000)
    rkDi = atomicAdd(&lh[bDi], 1);
    rkDA = atomicAdd(&lh[64+bDA], 1);
  }
  __syncthreads();
  if(tid < 128) lb[tid] = atomicAdd(&bcnt[c*128 + tid], lh[tid]);
  __syncthreads();
  if(ok){
    int off = lb[bDi] + rkDi;
    if(off < SCAP)
      stDi[(c*64+bDi)*SCAP + off] = make_uint2((unsigned)rDi | ((unsigned)cDi<<16), __float_as_uint(vDi));
    else { int pos = atomicAdd(&Di_cur[rDi],1); Di_pairs[pos] = make_float2(__int_as_float(cDi), vDi); }
    off = lb[64+bDA] + rkDA;
    if(off < SCAP)
      stDA[(c*64+bDA)*SCAP + off] = make_uint2((unsigned)rDA | ((unsigned)cDA<<16), __float_as_uint(vDA));
    else { int pos = atomicAdd(&DA_cur[rDA],1); DA_pairs[pos] = make_float2(__int_as_float(cDA), vDA); }
  }
}

// ---- scatter phase B: place staged edges into CSR positions ----------------
__global__ void place_pairs(const uint2* __restrict__ stDi, const uint2* __restrict__ stDA,
                            const int* __restrict__ bcnt,
                            int* __restrict__ Di_cur, float2* __restrict__ Di_pairs,
                            int* __restrict__ DA_cur, float2* __restrict__ DA_pairs){
  int bg  = blockIdx.x & 127;
  int sub = blockIdx.x >> 7;                   // 0..3
  bool isDA = bg >= 64;
  int b = bg & 63;
  const uint2* st = isDA ? stDA : stDi;
  int* cur = isDA ? DA_cur : Di_cur;
  float2* pairs = isDA ? DA_pairs : Di_pairs;
  for(int c=0;c<8;++c){
    int n = min(bcnt[c*128 + bg], SCAP);
    const uint2* base = st + (size_t)(c*64+b)*SCAP;
    for(int j = sub*256 + threadIdx.x; j < n; j += 4*256){
      uint2 p = base[j];
      int row = p.x & 0xFFFF;
      int col = p.x >> 16;
      int pos = atomicAdd(&cur[row], 1);
      pairs[pos] = make_float2(__int_as_float(col), __uint_as_float(p.y));
    }
  }
}

// ---------------- weight convert: Wt[(2i+m)*128 + n][k] = bf16(W_m[i][k][n]) ----
__global__ void wconv(const float* __restrict__ W0, const float* __restrict__ Wl1,
                      unsigned short* __restrict__ Wt){
  __shared__ float tile[32][129];
  int b  = blockIdx.x >> 3;       // 60 = i*2+m
  int kt = blockIdx.x & 7;        // 8 k-tiles of 32
  int i = b>>1, m = b&1;
  const float* W = (m ? Wl1 : W0) + (size_t)i*32768;
  unsigned short* out = Wt + (size_t)b*32768;
  int tid = threadIdx.x;
  int n = tid & 127, kr = tid >> 7;            // 2 k-rows x 128 n per iter
  for(int kk = kr; kk < 32; kk += 2)
    tile[kk][n] = W[(kt*32 + kk)*128 + n];
  __syncthreads();
  int kp = tid & 31, n8 = tid >> 5;            // 8 n x 32 k' per iter
  for(int nn = n8; nn < 128; nn += 8)
    out[nn*256 + kt*32 + kp] = f2bf(tile[kp][nn]);
}

// ---------------- conv1 (+ elu stats) + odd-bias precompute ----
__global__ void conv1_kernel(const float* __restrict__ in, const float* __restrict__ W_in,
                             const float* __restrict__ b_in,
                             const float* __restrict__ be0, const float* __restrict__ be1,
                             const unsigned short* __restrict__ Wt,
                             float* __restrict__ v_raw, unsigned short* __restrict__ elu_v,
                             float* __restrict__ st1, float* __restrict__ oddb){
  __shared__ float pool[256];
  int tid = threadIdx.x;
  int stride = gridDim.x*256;
  int cpy = (blockIdx.x&7)*512;
  float ls=0.f, ls2=0.f;
  for(int idx = blockIdx.x*256+tid; idx < N_V*128; idx += stride){
    int n = idx>>7, c = idx&127;
    float v = b_in[c] + in[n*3]*W_in[c] + in[n*3+1]*W_in[128+c] + in[n*3+2]*W_in[256+c];
    v_raw[idx] = v;
    float ev = eluf(v);
    elu_v[idx] = f2bf(ev);
    ls += ev; ls2 += ev*ev;
  }
  int ch = tid & 127;
  pool[tid]=ls; __syncthreads();
  if(tid<128) atomicAdd(&st1[cpy+ch], pool[tid]+pool[tid+128]);
  __syncthreads();
  pool[tid]=ls2; __syncthreads();
  if(tid<128) atomicAdd(&st1[cpy+256+ch], pool[tid]+pool[tid+128]);
  for(int item = blockIdx.x*256+tid; item < LAYERS*2*128; item += stride){
    int b = item >> 7;          // i*2+m
    int i = b >> 1, m = b & 1;
    int j = item & 127;
    const float* bp = (m ? be1 : be0) + i*256 + 128;
    const unsigned short* wp = Wt + (size_t)b*32768 + j*256 + 128;
    float s = 0.f;
    #pragma unroll 8
    for(int k=0;k<128;++k) s += bp[k]*bf2f(wp[k]);
    oddb[item] = s;
  }
}

// ---------------- SpMM: 8 rows per wave, 8 lanes per row (4 ch each) ----------
// Cooperative pairs load + shfl distribute; bf16 output; per-XCD fp32 stats.
__global__ __launch_bounds__(256) void spmm_bn(
    const int* __restrict__ ptr, const float2* __restrict__ pairs,
    const unsigned short* __restrict__ x, unsigned short* __restrict__ y, int nrows,
    float* __restrict__ stslot){
  __shared__ float pool[512];
  int tid = threadIdx.x;
  int w = tid>>6, lane = tid&63;
  int slot = lane>>3, jg = lane&7;
  int gbase = slot*8;                 // first lane of this row-group
  int row = blockIdx.x*32 + w*8 + slot;
  float4 acc = make_float4(0,0,0,0);
  if(row < nrows){
    int s0 = ptr[row], e0 = ptr[row+1];
    int last = e0 - 1;
    for(int base = s0; base < e0; base += 16){
      float2 pa = pairs[min(base + jg, last)];
      ushort4 xv[16]; float wgt[16];
      #pragma unroll
      for(int u=0;u<8;++u){
        float px = __shfl(pa.x, gbase + u);
        wgt[u] = (base + u <= last) ? __shfl(pa.y, gbase + u) : 0.f;
        xv[u] = *(const ushort4*)&x[(__float_as_int(px)<<5) + jg*4];
      }
      bool half2 = (base + 8 <= last);          // uniform within the group
      if(half2){
        float2 pb = pairs[min(base + 8 + jg, last)];
        #pragma unroll
        for(int u=0;u<8;++u){
          float px = __shfl(pb.x, gbase + u);
          wgt[8+u] = (base + 8 + u <= last) ? __shfl(pb.y, gbase + u) : 0.f;
          xv[8+u] = *(const ushort4*)&x[(__float_as_int(px)<<5) + jg*4];
        }
      }
      #pragma unroll
      for(int u=0;u<8;++u){
        acc.x += wgt[u]*bf2f(xv[u].x);
        acc.y += wgt[u]*bf2f(xv[u].y);
        acc.z += wgt[u]*bf2f(xv[u].z);
        acc.w += wgt[u]*bf2f(xv[u].w);
      }
      if(half2){
        #pragma unroll
        for(int u=8;u<16;++u){
          acc.x += wgt[u]*bf2f(xv[u].x);
          acc.y += wgt[u]*bf2f(xv[u].y);
          acc.z += wgt[u]*bf2f(xv[u].z);
          acc.w += wgt[u]*bf2f(xv[u].w);
        }
      }
    }
    ushort4 yo;
    yo.x = f2bf(acc.x); yo.y = f2bf(acc.y); yo.z = f2bf(acc.z); yo.w = f2bf(acc.w);
    *(ushort4*)&y[(row<<5) + jg*4] = yo;
  }
  float4 ls2 = make_float4(acc.x*acc.x, acc.y*acc.y, acc.z*acc.z, acc.w*acc.w);
  acc.x += __shfl_xor(acc.x, 32); acc.y += __shfl_xor(acc.y, 32);
  acc.z += __shfl_xor(acc.z, 32); acc.w += __shfl_xor(acc.w, 32);
  ls2.x += __shfl_xor(ls2.x, 32); ls2.y += __shfl_xor(ls2.y, 32);
  ls2.z += __shfl_xor(ls2.z, 32); ls2.w += __shfl_xor(ls2.w, 32);
  if(slot < 4) *(float4*)&pool[w*128 + slot*32 + jg*4] = acc;
  __syncthreads();
  int cpy = (blockIdx.x&7)*512;
  if(tid < 128){
    int c = (tid + (blockIdx.x<<3)) & 127;
    atomicAdd(&stslot[cpy+128+c], pool[c]+pool[128+c]+pool[256+c]+pool[384+c]);
  }
  __syncthreads();
  if(slot < 4) *(float4*)&pool[w*128 + slot*32 + jg*4] = ls2;
  __syncthreads();
  if(tid < 128){
    int c = (tid + (blockIdx.x<<3)) & 127;
    atomicAdd(&stslot[cpy+384+c], pool[c]+pool[128+c]+pool[256+c]+pool[384+c]);
  }
}

// ---------------- MFMA GEMM: A0 bf16 (k<128), A1 bf16 (k>=128, spmm out). ----
// Compile-time KT: K-loop fully unrolls (all loads issue up front).
// Stats in: sum of 8 per-XCD copies. Stats out: per-XCD copy (blockIdx&7).
template<int KT>
__global__ __launch_bounds__(256) void gemm_mfma(
    const unsigned short* __restrict__ A0, const unsigned short* __restrict__ A1,
    const float* __restrict__ st, float invM,
    const float* __restrict__ g, const float* __restrict__ be,
    const unsigned short* __restrict__ Wt, const float* __restrict__ bias,
    const float* __restrict__ bias2, const float* __restrict__ resid,
    float* __restrict__ out_raw, unsigned short* __restrict__ out_elu,
    float* __restrict__ stE, float* __restrict__ stR, int M)
{
  __shared__ float ab[256], bb[256];
  int tid = threadIdx.x;
  if(tid < KT){
    float s1 = 0.f, s2v = 0.f;
    #pragma unroll
    for(int c8=0;c8<8;++c8){ s1 += st[c8*512 + tid]; s2v += st[c8*512 + 256 + tid]; }
    float mean = s1*invM;
    float var  = fmaxf(s2v*invM - mean*mean, 0.f);
    float aa   = g[tid]*rsqrtf(var + 1e-5f);
    ab[tid] = aa; bb[tid] = be[tid] - mean*aa;
  }
  __syncthreads();

  int wave = tid>>6, lane = tid&63;
  int ln = lane&15, q = lane>>4;
  int r0 = blockIdx.x*16;
  int c0 = wave*32;
  int kq = q*8;
  int arow = r0 + ln;
  bool aok = arow < M;

  f32x4 acc[2] = {};
  #pragma unroll
  for(int kb=0; kb<KT; kb+=32){
    int kg = kb + kq;
    BFu af;
    if(!aok){
      #pragma unroll
      for(int j2=0;j2<8;++j2) af.us[j2] = 0;
    } else {
      const unsigned short* Ap = (A1 && kb >= 128) ? &A1[arow*128 + kg - 128]
                                                   : &A0[arow*128 + kg];
      BFu raw; raw.u = *(const uint4*)Ap;
      #pragma unroll
      for(int j2=0;j2<8;++j2) af.us[j2] = f2bf(fmaf(bf2f(raw.us[j2]), ab[kg+j2], bb[kg+j2]));
    }
    #pragma unroll
    for(int nb=0;nb<2;++nb){
      int n = c0 + nb*16 + ln;
      BFu bfv; bfv.u = *(const uint4*)&Wt[n*256 + kb + kq];
      acc[nb] = __builtin_amdgcn_mfma_f32_16x16x32_bf16(af.s8, bfv.s8, acc[nb], 0, 0, 0);
    }
  }

  int rbase = r0 + q*4;
  bool wantR = (stR != nullptr);
  int cpy = (blockIdx.x&7)*512;
  #pragma unroll
  for(int nb=0;nb<2;++nb){
    int col = c0 + nb*16 + ln;
    float bsum = bias[col] + (bias2 ? bias2[col] : 0.f);
    float s=0.f, s2=0.f, rs=0.f, rs2=0.f;
    #pragma unroll
    for(int reg=0;reg<4;++reg){
      int row = rbase + reg;
      bool ok = row < M;
      float v = acc[nb][reg] + bsum;
      if(resid && ok) v += resid[row*128 + col];
      float ve = eluf(v);
      if(ok){
        if(out_raw) out_raw[row*128 + col] = v;
        if(out_elu) out_elu[row*128 + col] = f2bf(ve);
        s += ve; s2 += ve*ve;
        if(wantR){ rs += v; rs2 += v*v; }
      }
    }
    s  += __shfl_xor(s, 16);  s  += __shfl_xor(s, 32);
    s2 += __shfl_xor(s2, 16); s2 += __shfl_xor(s2, 32);
    if(wantR){
      rs  += __shfl_xor(rs, 16);  rs  += __shfl_xor(rs, 32);
      rs2 += __shfl_xor(rs2, 16); rs2 += __shfl_xor(rs2, 32);
    }
    if(q==0){
      if(stE){ atomicAdd(&stE[cpy+col], s); atomicAdd(&stE[cpy+256+col], s2); }
      if(wantR){ atomicAdd(&stR[cpy+col], rs); atomicAdd(&stR[cpy+256+col], rs2); }
    }
  }
}

// ---------------- final: BN(v) @ W_out + b_out, elu ------------------
__global__ void final_kernel(const float* __restrict__ v_raw, const float* __restrict__ st,
                             const float* __restrict__ g2, const float* __restrict__ be2,
                             const float* __restrict__ W_out, const float* __restrict__ b_out,
                             float* __restrict__ out){
  __shared__ float pool[256];
  int tid = threadIdx.x; int half = tid>>7, k = tid&127;
  float s1 = 0.f, s2v = 0.f;
  #pragma unroll
  for(int c8=0;c8<8;++c8){ s1 += st[c8*512 + k]; s2v += st[c8*512 + 256 + k]; }
  float mean = s1*(1.f/N_V);
  float var = fmaxf(s2v*(1.f/N_V) - mean*mean, 0.f);
  float aa = g2[k]*rsqrtf(var+1e-5f);
  float scale = aa*W_out[k];
  float cons = (be2[k]-mean*aa)*W_out[k];
  int r = blockIdx.x*2 + half;
  float val = v_raw[r*128+k]*scale + cons;
  pool[tid]=val; __syncthreads();
  for(int s=64;s>=1;s>>=1){ if(k<s) pool[tid]+=pool[tid+s]; __syncthreads(); }
  if(k==0) out[r] = eluf(pool[tid] + b_out[0]);
}

extern "C" void kernel_launch(void* const* d_in, const int* in_sizes, int n_in,
                              void* d_out, int out_size, void* d_ws, size_t ws_size,
                              hipStream_t stream){
  const float* inputs  = (const float*)d_in[0];
  const int*   Di_rows = (const int*)d_in[2];
  const int*   Di_cols = (const int*)d_in[3];
  const float* Di_vals = (const float*)d_in[4];
  const int*   DiA_rows= (const int*)d_in[5];
  const int*   DiA_cols= (const int*)d_in[6];
  const float* DiA_vals= (const float*)d_in[7];
  const float* W_in = (const float*)d_in[8];  const float* b_in = (const float*)d_in[9];
  const float* g0  = (const float*)d_in[10];  const float* be0 = (const float*)d_in[11];
  const float* W0  = (const float*)d_in[12];  const float* b0  = (const float*)d_in[13];
  const float* g1  = (const float*)d_in[14];  const float* be1 = (const float*)d_in[15];
  const float* Wl1 = (const float*)d_in[16];  const float* bl1 = (const float*)d_in[17];
  const float* g2  = (const float*)d_in[18];  const float* be2 = (const float*)d_in[19];
  const float* W_out = (const float*)d_in[20]; const float* b_out = (const float*)d_in[21];

  float* ws = (float*)d_ws;
  float* v_raw = ws;                                        // 640000 f
  unsigned short* elu_v0 = (unsigned short*)(ws + 640000);  // 640000 us
  unsigned short* elu_v1 = (unsigned short*)(ws + 960000);  // 640000 us
  unsigned short* elu_f0 = (unsigned short*)(ws + 1280000); // 1280000 us -> f 1280000..1920000
  unsigned short* Dv16  = (unsigned short*)(ws + 2560000);  // 1280000 us (bf16)
  unsigned short* DAf16 = (unsigned short*)(ws + 3840000);  // 640000 us (bf16)
  float* st    = ws + 4480000;             // 64 slots x 4096 = 262144 f (slot 63 = bcnt)
  float* oddb  = ws + 4742144;             // 7680
  int* Di_ptr  = (int*)(ws + 4749824);     // 40001
  int* DA_ptr  = (int*)(ws + 4789825);     // 20001
  int* Di_cur  = (int*)(ws + 4809826);     // 40000 (init by addback)
  int* DA_cur  = (int*)(ws + 4849826);     // 20000 (init by addback)
  float2* Di_pairs = (float2*)(ws + 4869826);  // 960000 floats (even -> 8B aligned)
  float2* DA_pairs = (float2*)(ws + 5829826);  // 960000 floats
  int* bsumDi  = (int*)(ws + 6789826);     // 256
  int* bsumDA  = (int*)(ws + 6790082);     // 128
  unsigned short* Wt = (unsigned short*)(ws + 6790212);     // 60*32768 us
  unsigned short* elu_f1 = (unsigned short*)(ws + 7773252); // 1280000 us
  unsigned short* elu_x1 = Dv16;                            // odd layers only
  // staging (setup-only) spans the dead region f 1280000..3737600.
  uint2* stDi = (uint2*)(ws + 1280000);    // 8*64*1200 uint2 -> ends 2508800
  uint2* stDA = (uint2*)(ws + 2508800);    // -> ends 3737600
  // hist copies alias the (not-yet-written) Di_pairs region
  int* Di_hist = (int*)Di_pairs;           // 320000 ints
  int* DA_hist = Di_hist + 320000;         // 160000 ints (contiguous -> one memset)
  int* bcnt    = (int*)(st + (size_t)63*STC);  // 8*128=1024 ints, zeroed by st memset

  unsigned short* Vb[2] = {elu_v0, elu_v1};
  unsigned short* Fb[2] = {elu_f0, elu_f1};

  hipMemsetAsync(st, 0, (size_t)64*STC*sizeof(float), stream);
  hipMemsetAsync(Di_hist, 0, (size_t)480000*sizeof(int), stream);

  hist_both<<<1875, 256, 0, stream>>>(Di_rows, DiA_rows, Di_hist, DA_hist);
  chunkscan<<<236, 256, 0, stream>>>(Di_hist, Di_ptr, DA_hist, DA_ptr, bsumDi, bsumDA);
  topscan<<<2, 256, 0, stream>>>(bsumDi, bsumDA);
  addback<<<236, 256, 0, stream>>>(Di_ptr, Di_cur, bsumDi, DA_ptr, DA_cur, bsumDA);
  stage_pairs<<<1875, 256, 0, stream>>>(Di_rows, Di_cols, Di_vals,
                                        DiA_rows, DiA_cols, DiA_vals,
                                        stDi, stDA, bcnt,
                                        Di_cur, Di_pairs, DA_cur, DA_pairs);
  place_pairs<<<512, 256, 0, stream>>>(stDi, stDA, bcnt,
                                       Di_cur, Di_pairs, DA_cur, DA_pairs);
  // elu_f0 overlaps the staging region -> zero it only after place_pairs.
  hipMemsetAsync(elu_f0, 0, (size_t)1280000*sizeof(unsigned short), stream);
  wconv<<<480, 256, 0, stream>>>(W0, Wl1, Wt);
  conv1_kernel<<<640, 256, 0, stream>>>(inputs, W_in, b_in, be0, be1, Wt,
                                        v_raw, elu_v0, st + STC, oddb);

  int pv = 0, pf = 0;
  for(int i=0;i<LAYERS;++i){
    if((i&1)==0){
      float* S0  = st + (size_t)(2*i)*STC;
      float* S1b = st + (size_t)(2*i+1)*STC;
      spmm_bn<<<1250, 256, 0, stream>>>(Di_ptr, Di_pairs, Vb[pv], Dv16, 40000, S0);
      gemm_mfma<256><<<625, 256, 0, stream>>>(Fb[pf], Dv16, S0, 1.f/N_F, g0+i*256, be0+i*256,
                                         Wt + (size_t)(2*i)*32768, b0+i*128, nullptr,
                                         nullptr, nullptr, Fb[pf^1],
                                         st+(size_t)(2*(i+2))*STC, nullptr, N_F);
      pf ^= 1;
      spmm_bn<<<625, 256, 0, stream>>>(DA_ptr, DA_pairs, Fb[pf], DAf16, 20000, S1b);
      gemm_mfma<256><<<313, 256, 0, stream>>>(Vb[pv], DAf16, S1b, 1.f/N_V, g1+i*256, be1+i*256,
                                         Wt + (size_t)(2*i+1)*32768, bl1+i*128, nullptr,
                                         v_raw, v_raw, Vb[pv^1],
                                         st+(size_t)(2*(i+1))*STC, nullptr, N_V);
      pv ^= 1;
    } else {
      float* S0  = st + (size_t)(2*i)*STC;
      float* S1b = st + (size_t)(2*i+1)*STC;
      gemm_mfma<128><<<313, 256, 0, stream>>>(Vb[pv], nullptr, S0, 1.f/N_V, g0+i*256, be0+i*256,
                                         Wt + (size_t)(2*i)*32768, b0+i*128, oddb+i*256,
                                         nullptr, nullptr, elu_x1,
                                         S1b, nullptr, N_V);
      float* stE = (i==LAYERS-1) ? nullptr : st+(size_t)(2*i+3)*STC;
      float* stR = (i==LAYERS-1) ? st+(size_t)62*STC : nullptr;
      gemm_mfma<128><<<313, 256, 0, stream>>>(elu_x1, nullptr, S1b, 1.f/N_V, g1+i*256, be1+i*256,
                                         Wt + (size_t)(2*i+1)*32768, bl1+i*128, oddb+i*256+128,
                                         v_raw, v_raw, Vb[pv],
                                         stE, stR, N_V);
    }
  }
  final_kernel<<<2500, 256, 0, stream>>>(v_raw, st+(size_t)62*STC, g2, be2, W_out, b_out,
                                         (float*)d_out);
}